// Round 5
// baseline (5099.343 us; speedup 1.0000x reference)
//
#include <hip/hip_runtime.h>
#include <cstdint>
#include <cstddef>

// DGCNN forward, fp32. R5:
//  - knn decoupled: knn_dist (pure tiled Gram -> negd buffer, 2-batch chunks,
//    L3-resident, aliases conv featB scratch) + knn_select (streams negd rows,
//    theta-mask top-20, in-wave shfl merge -> final idx). R4's spill disaster
//    came from forcing occupancy on a kernel carrying 40 regs of list state;
//    now GEMM kernel has no lists and select kernel has no GEMM.
//  - conv k-split x2 retained.

constexpr int NB = 8;
constexpr int NP = 2048;
constexpr int KK = 20;

#define FMA16(AV, BV, ACC)                                          \
  {                                                                 \
    const float _a[4] = {AV.x, AV.y, AV.z, AV.w};                   \
    const float _b[4] = {BV.x, BV.y, BV.z, BV.w};                   \
    _Pragma("unroll")                                               \
    for (int _e = 0; _e < 4; ++_e) {                                \
      _Pragma("unroll")                                             \
      for (int _f = 0; _f < 4; ++_f)                                \
        ACC[_e][_f] = fmaf(_a[_e], _b[_f], ACC[_e][_f]);            \
    }                                                               \
  }

// ---------------- pad x -> x4 ----------------
__global__ __launch_bounds__(256) void pad_kernel(const float* __restrict__ x,
                                                  float* __restrict__ x4) {
  const int p = blockIdx.x * 256 + threadIdx.x;  // 16384 points
  float4 v;
  v.x = x[p * 3 + 0]; v.y = x[p * 3 + 1]; v.z = x[p * 3 + 2]; v.w = 0.f;
  *reinterpret_cast<float4*>(x4 + (size_t)p * 4) = v;
}

// ---------------- norms ----------------
template<int C, int RS>
__global__ __launch_bounds__(256) void norms_kernel(const float* __restrict__ X,
                                                    float* __restrict__ out) {
  const int g = blockIdx.x * 256 + threadIdx.x;  // 0 .. NB*NP-1
  const float* p = X + (size_t)g * RS;
  float s = 0.f;
#pragma unroll
  for (int c = 0; c < C; ++c) s = fmaf(p[c], p[c], s);
  out[g] = s;
}

// ---------------- knn distances: pure tiled Gram -> negd ----------------
// Block: 64x64 tile of batch (bbase + blockIdx.z). negd[z][i][j] = 2*dot - ni - nj.
// LDS: XiT chunk [0,4096) | XjT chunk [4096,8192) | ni/nj [8192,8320). 33 KB.
template<int C, int CHUNK, int NCH, int RS>
__global__ __launch_bounds__(256) void knn_dist_kernel(const float* __restrict__ X,
    const float* __restrict__ norms, float* __restrict__ negd, int bbase) {
  constexpr bool SMALL = (CHUNK == 4);
  constexpr int XJ = SMALL ? 256 : 4096;
  constexpr int NIO = SMALL ? 512 : 8192;
  __shared__ float sb[NIO + 128];

  const int t = threadIdx.x, lane = t & 63, wid = t >> 6, tr = t & 15, tc = t >> 4;
  const int z = blockIdx.z, b = bbase + z;
  const int i0 = blockIdx.x * 64, j0 = blockIdx.y * 64;

  if (t < 64) sb[NIO + t] = norms[b * NP + i0 + t];
  else if (t < 128) sb[NIO + t] = norms[b * NP + j0 + (t - 64)];

  float acc[4][4] = {};
#pragma unroll
  for (int cc = 0; cc < NCH; ++cc) {
    __syncthreads();
    if constexpr (SMALL) {
      const int c = t >> 6, row = t & 63;
      sb[c * 64 + row] = X[(size_t)(b * NP + i0 + row) * RS + c];
      sb[XJ + c * 64 + row] = X[(size_t)(b * NP + j0 + row) * RS + c];
    } else {
#pragma unroll
      for (int i = 0; i < CHUNK / 16; ++i) {
        const int q = wid + i * 4;
        const float4 v = *reinterpret_cast<const float4*>(
            X + (size_t)(b * NP + i0 + lane) * RS + cc * CHUNK + q * 4);
        sb[(q * 4 + 0) * 64 + lane] = v.x;
        sb[(q * 4 + 1) * 64 + lane] = v.y;
        sb[(q * 4 + 2) * 64 + lane] = v.z;
        sb[(q * 4 + 3) * 64 + lane] = v.w;
        const float4 u = *reinterpret_cast<const float4*>(
            X + (size_t)(b * NP + j0 + lane) * RS + cc * CHUNK + q * 4);
        sb[XJ + (q * 4 + 0) * 64 + lane] = u.x;
        sb[XJ + (q * 4 + 1) * 64 + lane] = u.y;
        sb[XJ + (q * 4 + 2) * 64 + lane] = u.z;
        sb[XJ + (q * 4 + 3) * 64 + lane] = u.w;
      }
    }
    __syncthreads();
#pragma unroll
    for (int c = 0; c < CHUNK; ++c) {
      const float4 a = *reinterpret_cast<const float4*>(sb + c * 64 + tr * 4);
      const float4 bb = *reinterpret_cast<const float4*>(sb + XJ + c * 64 + tc * 4);
      FMA16(a, bb, acc);
    }
  }

  // negd = 2*dot - |xi|^2 - |xj|^2
#pragma unroll
  for (int e = 0; e < 4; ++e) {
    const int row = tr * 4 + e;
    const float ni = sb[NIO + row];
    float4 nd;
    nd.x = 2.f * acc[e][0] - ni - sb[NIO + 64 + tc * 4 + 0];
    nd.y = 2.f * acc[e][1] - ni - sb[NIO + 64 + tc * 4 + 1];
    nd.z = 2.f * acc[e][2] - ni - sb[NIO + 64 + tc * 4 + 2];
    nd.w = 2.f * acc[e][3] - ni - sb[NIO + 64 + tc * 4 + 3];
    *reinterpret_cast<float4*>(negd + ((size_t)z * NP + i0 + row) * NP + j0 + tc * 4) = nd;
  }
}

// ---------------- knn select: stream negd rows, top-20 per row ----------------
// 4 selector lanes per row, each scans a CONTIGUOUS 512-range (stable tie order).
// theta = max of the 4 lists' mins (safe exclusion threshold), 16-wide pass-mask +
// ffs-drain, in-wave shfl merge, direct idx write. No LDS, small VGPR footprint.
__global__ __launch_bounds__(256) void knn_select_kernel(const float* __restrict__ negd,
    int* __restrict__ idxout, int bbase) {
  const int t = threadIdx.x, lane = t & 63;
  const int rsel = t >> 2, qsel = t & 3;
  const int rloc = blockIdx.x * 64 + rsel;  // 0..4095 within 2-batch chunk
  const float* rowp = negd + (size_t)rloc * NP + qsel * 512;

  float lv[KK]; int li[KK];
  float minv = -__builtin_inff(); int minpos = 0;
  float theta = -__builtin_inff();

  auto ins = [&](float nv, int nj) {
    if (nv > minv) {  // strict > keeps earlier (lower-j) on ties (stable top-k)
#pragma unroll
      for (int e = 0; e < KK; ++e)
        if (e == minpos) { lv[e] = nv; li[e] = nj; }
      minv = lv[0]; minpos = 0;
#pragma unroll
      for (int e = 1; e < KK; ++e)
        if (lv[e] < minv) { minv = lv[e]; minpos = e; }
    }
  };

  for (int tt = 0; tt < 32; ++tt) {
    const int jb0 = qsel * 512 + tt * 16;
    if (tt == 0) {
#pragma unroll
      for (int m = 0; m < 4; ++m) {
        const float4 dv = *reinterpret_cast<const float4*>(rowp + tt * 16 + m * 4);
        const int jb = jb0 + m * 4;
        lv[m * 4 + 0] = dv.x; li[m * 4 + 0] = jb + 0;
        lv[m * 4 + 1] = dv.y; li[m * 4 + 1] = jb + 1;
        lv[m * 4 + 2] = dv.z; li[m * 4 + 2] = jb + 2;
        lv[m * 4 + 3] = dv.w; li[m * 4 + 3] = jb + 3;
      }
    } else if (tt == 1) {
      {
        const float4 dv = *reinterpret_cast<const float4*>(rowp + tt * 16);
        lv[16] = dv.x; li[16] = jb0 + 0;
        lv[17] = dv.y; li[17] = jb0 + 1;
        lv[18] = dv.z; li[18] = jb0 + 2;
        lv[19] = dv.w; li[19] = jb0 + 3;
      }
      minv = lv[0]; minpos = 0;
#pragma unroll
      for (int e = 1; e < KK; ++e)
        if (lv[e] < minv) { minv = lv[e]; minpos = e; }
#pragma unroll
      for (int m = 1; m < 4; ++m) {
        const float4 dv = *reinterpret_cast<const float4*>(rowp + tt * 16 + m * 4);
        const int jb = jb0 + m * 4;
        ins(dv.x, jb + 0); ins(dv.y, jb + 1); ins(dv.z, jb + 2); ins(dv.w, jb + 3);
      }
      theta = fmaxf(minv, __shfl_xor(minv, 1));
      theta = fmaxf(theta, __shfl_xor(theta, 2));
    } else {
      unsigned mask = 0;
      float vals[16];
#pragma unroll
      for (int m = 0; m < 4; ++m) {
        const float4 dv = *reinterpret_cast<const float4*>(rowp + tt * 16 + m * 4);
        vals[m * 4 + 0] = dv.x; vals[m * 4 + 1] = dv.y;
        vals[m * 4 + 2] = dv.z; vals[m * 4 + 3] = dv.w;
        mask |= (dv.x >= theta ? 1u : 0u) << (m * 4 + 0);
        mask |= (dv.y >= theta ? 1u : 0u) << (m * 4 + 1);
        mask |= (dv.z >= theta ? 1u : 0u) << (m * 4 + 2);
        mask |= (dv.w >= theta ? 1u : 0u) << (m * 4 + 3);
      }
      while (__any(mask != 0u)) {
        if (mask) {
          const int sB = __ffs(mask) - 1;
          mask &= mask - 1;
          float vv = vals[0];
#pragma unroll
          for (int e = 1; e < 16; ++e)
            if (e == sB) vv = vals[e];
          ins(vv, jb0 + sB);
        }
      }
      theta = fmaxf(minv, __shfl_xor(minv, 1));
      theta = fmaxf(theta, __shfl_xor(theta, 2));
    }
  }

  // merge the 4 selector lists in-wave (selector 0 range has lowest j: stable)
  const int base = lane & ~3;
  for (int sq = 1; sq < 4; ++sq) {
#pragma unroll
    for (int e = 0; e < KK; ++e) {
      const float v = __shfl(lv[e], base + sq);
      const int j = __shfl(li[e], base + sq);
      if (qsel == 0) ins(v, j);
    }
  }
  if (qsel == 0) {
    int* op = idxout + (size_t)(bbase * NP + rloc) * KK;
#pragma unroll
    for (int e = 0; e < KK; ++e) op[e] = li[e];
  }
}

// ---------------- edge conv (k-split x2 via blockIdx.y) ----------------
template<int C, int CHUNK, int NCH, int O, int RSIN>
__global__ __launch_bounds__(256) void conv_kernel(const float* __restrict__ X,
    const int* __restrict__ nbr, const float* __restrict__ W,
    const float* __restrict__ bias, float* __restrict__ outf,
    float* __restrict__ outfB, float* __restrict__ ssum, float* __restrict__ ssq) {
  constexpr int CC = NCH * CHUNK;
  constexpr int WREG = (CC * 64 > 2048) ? CC * 64 : 2048;  // W1T region (stats alias)
  constexpr int AB = WREG;                                 // A-chunk region
  constexpr int SBF = WREG + CHUNK * 64;
  __shared__ float sb[SBF];
  constexpr int WS = 2 * C;
  constexpr int OB = O / 64;

  const int t = threadIdx.x, lane = t & 63, wid = t >> 6, tr = t & 15, tc = t >> 4;
  const int b = blockIdx.z, n0 = blockIdx.x * 64;
  const int oy = blockIdx.y % OB, ks = blockIdx.y / OB;
  const int o0 = oy * 64;
  const int kbeg = ks * (KK / 2), kend = kbeg + (KK / 2);

  float T[4][4];
  {
    float acc[4][4] = {};
#pragma unroll
    for (int cc = 0; cc < NCH; ++cc) {
      __syncthreads();
      if constexpr (CHUNK == 4) {
        const int c = t >> 6, row = t & 63;
        sb[AB + c * 64 + row] = (c < C) ? X[(size_t)(b * NP + n0 + row) * RSIN + c] : 0.f;
        sb[c * 64 + row] = (c < C) ? (W[(o0 + row) * WS + C + c] - W[(o0 + row) * WS + c]) : 0.f;
      } else {
#pragma unroll
        for (int i = 0; i < CHUNK / 16; ++i) {
          const int q = wid + i * 4;
          const float4 v = *reinterpret_cast<const float4*>(
              X + (size_t)(b * NP + n0 + lane) * RSIN + cc * CHUNK + q * 4);
          sb[AB + (q * 4 + 0) * 64 + lane] = v.x;
          sb[AB + (q * 4 + 1) * 64 + lane] = v.y;
          sb[AB + (q * 4 + 2) * 64 + lane] = v.z;
          sb[AB + (q * 4 + 3) * 64 + lane] = v.w;
          const float4 w1 = *reinterpret_cast<const float4*>(
              W + (size_t)(o0 + lane) * WS + cc * CHUNK + q * 4);
          const float4 w2 = *reinterpret_cast<const float4*>(
              W + (size_t)(o0 + lane) * WS + C + cc * CHUNK + q * 4);
          sb[(q * 4 + 0) * 64 + lane] = w2.x - w1.x;
          sb[(q * 4 + 1) * 64 + lane] = w2.y - w1.y;
          sb[(q * 4 + 2) * 64 + lane] = w2.z - w1.z;
          sb[(q * 4 + 3) * 64 + lane] = w2.w - w1.w;
        }
      }
      __syncthreads();
#pragma unroll
      for (int c = 0; c < CHUNK; ++c) {
        const float4 a = *reinterpret_cast<const float4*>(sb + AB + c * 64 + tr * 4);
        const float4 bb = *reinterpret_cast<const float4*>(sb + c * 64 + tc * 4);
        FMA16(a, bb, acc);
      }
    }
    const float4 bv = *reinterpret_cast<const float4*>(bias + o0 + tc * 4);
    const float bva[4] = {bv.x, bv.y, bv.z, bv.w};
#pragma unroll
    for (int e = 0; e < 4; ++e) {
#pragma unroll
      for (int f = 0; f < 4; ++f) T[e][f] = acc[e][f] + bva[f];
    }
  }

  // stage full W1T
  __syncthreads();
  if constexpr (CHUNK == 4) {
    const int c = t >> 6, row = t & 63;
    sb[c * 64 + row] = (c < C) ? W[(o0 + row) * WS + c] : 0.f;
  } else {
#pragma unroll
    for (int i = 0; i < CC / 16; ++i) {
      const int q = wid + i * 4;
      const float4 w1 = *reinterpret_cast<const float4*>(
          W + (size_t)(o0 + lane) * WS + q * 4);
      sb[(q * 4 + 0) * 64 + lane] = w1.x;
      sb[(q * 4 + 1) * 64 + lane] = w1.y;
      sb[(q * 4 + 2) * 64 + lane] = w1.z;
      sb[(q * 4 + 3) * 64 + lane] = w1.w;
    }
  }

  float mx[4][4], sm[4][4], s2[4][4];
#pragma unroll
  for (int e = 0; e < 4; ++e) {
#pragma unroll
    for (int f = 0; f < 4; ++f) { mx[e][f] = -__builtin_inff(); sm[e][f] = 0.f; s2[e][f] = 0.f; }
  }

  for (int k = kbeg; k < kend; ++k) {
    const int jr = nbr[(size_t)(b * NP + n0 + lane) * KK + k];
    float acc[4][4] = {};
#pragma unroll
    for (int cc = 0; cc < NCH; ++cc) {
      __syncthreads();
      if constexpr (CHUNK == 4) {
        const int c = t >> 6, row = t & 63;
        const int jrr = nbr[(size_t)(b * NP + n0 + row) * KK + k];
        sb[AB + c * 64 + row] = (c < C) ? X[(size_t)(b * NP + jrr) * RSIN + c] : 0.f;
      } else {
#pragma unroll
        for (int i = 0; i < CHUNK / 16; ++i) {
          const int q = wid + i * 4;
          const float4 v = *reinterpret_cast<const float4*>(
              X + (size_t)(b * NP + jr) * RSIN + cc * CHUNK + q * 4);
          sb[AB + (q * 4 + 0) * 64 + lane] = v.x;
          sb[AB + (q * 4 + 1) * 64 + lane] = v.y;
          sb[AB + (q * 4 + 2) * 64 + lane] = v.z;
          sb[AB + (q * 4 + 3) * 64 + lane] = v.w;
        }
      }
      __syncthreads();
#pragma unroll
      for (int c = 0; c < CHUNK; ++c) {
        const float4 a = *reinterpret_cast<const float4*>(sb + AB + c * 64 + tr * 4);
        const float4 bb = *reinterpret_cast<const float4*>(sb + (cc * CHUNK + c) * 64 + tc * 4);
        FMA16(a, bb, acc);
      }
    }
#pragma unroll
    for (int e = 0; e < 4; ++e) {
#pragma unroll
      for (int f = 0; f < 4; ++f) {
        const float h = acc[e][f] + T[e][f];
        mx[e][f] = fmaxf(mx[e][f], h);
        sm[e][f] += h;
        s2[e][f] = fmaf(h, h, s2[e][f]);
      }
    }
  }

  // write max-over-k-half (pre-BN)
  {
    float* dst = (ks == 0) ? outf : outfB;
    const int dstride = (ks == 0) ? 512 : O;
#pragma unroll
    for (int e = 0; e < 4; ++e) {
      float4 o4;
      o4.x = mx[e][0]; o4.y = mx[e][1]; o4.z = mx[e][2]; o4.w = mx[e][3];
      *reinterpret_cast<float4*>(dst + (size_t)(b * NP + n0 + tr * 4 + e) * dstride + o0 + tc * 4) = o4;
    }
  }

  __syncthreads();
#pragma unroll
  for (int f = 0; f < 4; ++f) {
    sb[tr * 64 + tc * 4 + f] = sm[0][f] + sm[1][f] + sm[2][f] + sm[3][f];
    sb[1024 + tr * 64 + tc * 4 + f] = s2[0][f] + s2[1][f] + s2[2][f] + s2[3][f];
  }
  __syncthreads();
  if (t < 64) {
    float S = 0.f, Q = 0.f;
#pragma unroll
    for (int r = 0; r < 16; ++r) { S += sb[r * 64 + t]; Q += sb[1024 + r * 64 + t]; }
    atomicAdd(ssum + o0 + t, S);
    atomicAdd(ssq + o0 + t, Q);
  }
}

// ---------------- bn + leaky relu (merge k-halves, post-max) ----------------
template<int O>
__global__ __launch_bounds__(256) void bnrelu_kernel(float* __restrict__ feat,
    const float* __restrict__ featB,
    const float* __restrict__ ssum, const float* __restrict__ ssq,
    const float* __restrict__ g, const float* __restrict__ be) {
  constexpr float INV = 1.0f / 327680.0f;  // B*N*K
  const int t4 = blockIdx.x * 256 + threadIdx.x;
  const int e0 = t4 * 4;
  const int r = e0 / O, c = e0 % O;
  float4 h = *reinterpret_cast<float4*>(feat + (size_t)r * 512 + c);
  const float4 h2 = *reinterpret_cast<const float4*>(featB + (size_t)r * O + c);
  float hv[4] = {fmaxf(h.x, h2.x), fmaxf(h.y, h2.y), fmaxf(h.z, h2.z), fmaxf(h.w, h2.w)};
#pragma unroll
  for (int j = 0; j < 4; ++j) {
    const int col = c + j;
    const float m = ssum[col] * INV;
    const float v = ssq[col] * INV - m * m;
    const float sc = g[col] / sqrtf(v + 1e-5f);
    const float val = (hv[j] - m) * sc + be[col];
    hv[j] = (val >= 0.f) ? val : 0.2f * val;
  }
  h.x = hv[0]; h.y = hv[1]; h.z = hv[2]; h.w = hv[3];
  *reinterpret_cast<float4*>(feat + (size_t)r * 512 + c) = h;
}

// ---------------- final conv + global max pool ----------------
__global__ __launch_bounds__(256) void final_kernel(const float* __restrict__ xcat,
    const float* __restrict__ Wf, unsigned int* __restrict__ outenc) {
  __shared__ float sb[9216];  // AT 4096 | WfT 4096 | mred 1024
  const int t = threadIdx.x, lane = t & 63, wid = t >> 6, tr = t & 15, tc = t >> 4;
  const int b = blockIdx.z, n0 = blockIdx.x * 64, o0 = blockIdx.y * 64;
  float acc[4][4] = {};
  for (int cc = 0; cc < 8; ++cc) {
    __syncthreads();
#pragma unroll
    for (int i = 0; i < 4; ++i) {
      const int q = wid + i * 4;
      const float4 v = *reinterpret_cast<const float4*>(
          xcat + (size_t)(b * NP + n0 + lane) * 512 + cc * 64 + q * 4);
      sb[(q * 4 + 0) * 64 + lane] = v.x;
      sb[(q * 4 + 1) * 64 + lane] = v.y;
      sb[(q * 4 + 2) * 64 + lane] = v.z;
      sb[(q * 4 + 3) * 64 + lane] = v.w;
      const float4 w4 = *reinterpret_cast<const float4*>(
          Wf + (size_t)(o0 + lane) * 512 + cc * 64 + q * 4);
      sb[4096 + (q * 4 + 0) * 64 + lane] = w4.x;
      sb[4096 + (q * 4 + 1) * 64 + lane] = w4.y;
      sb[4096 + (q * 4 + 2) * 64 + lane] = w4.z;
      sb[4096 + (q * 4 + 3) * 64 + lane] = w4.w;
    }
    __syncthreads();
#pragma unroll
    for (int c = 0; c < 64; ++c) {
      const float4 a = *reinterpret_cast<const float4*>(sb + c * 64 + tr * 4);
      const float4 bb = *reinterpret_cast<const float4*>(sb + 4096 + c * 64 + tc * 4);
      FMA16(a, bb, acc);
    }
  }
  float m4[4];
#pragma unroll
  for (int f = 0; f < 4; ++f)
    m4[f] = fmaxf(fmaxf(acc[0][f], acc[1][f]), fmaxf(acc[2][f], acc[3][f]));
  __syncthreads();
#pragma unroll
  for (int f = 0; f < 4; ++f) sb[8192 + tr * 64 + tc * 4 + f] = m4[f];
  __syncthreads();
  if (t < 64) {
    float M = -__builtin_inff();
#pragma unroll
    for (int r = 0; r < 16; ++r) M = fmaxf(M, sb[8192 + r * 64 + t]);
    const unsigned ubits = __float_as_uint(M);
    const unsigned key = (ubits & 0x80000000u) ? ~ubits : (ubits | 0x80000000u);
    atomicMax(outenc + b * 1024 + o0 + t, key);
  }
}

__global__ __launch_bounds__(256) void decode_kernel(const unsigned int* __restrict__ enc,
    const float* __restrict__ bf, float* __restrict__ out) {
  const int gid = blockIdx.x * 256 + threadIdx.x;  // 8192
  const unsigned key = enc[gid];
  const unsigned ubits = (key & 0x80000000u) ? (key & 0x7fffffffu) : ~key;
  out[gid] = __uint_as_float(ubits) + bf[gid & 1023];
}

// ---------------- launch ----------------
extern "C" void kernel_launch(void* const* d_in, const int* in_sizes, int n_in,
                              void* d_out, int out_size, void* d_ws, size_t ws_size,
                              hipStream_t stream) {
  (void)in_sizes; (void)n_in; (void)out_size; (void)ws_size;
  const float* x   = (const float*)d_in[0];
  const float* W0  = (const float*)d_in[1];
  const float* b0  = (const float*)d_in[2];
  const float* g0  = (const float*)d_in[3];
  const float* be0 = (const float*)d_in[4];
  const float* W1  = (const float*)d_in[5];
  const float* b1  = (const float*)d_in[6];
  const float* g1  = (const float*)d_in[7];
  const float* be1 = (const float*)d_in[8];
  const float* W2  = (const float*)d_in[9];
  const float* b2  = (const float*)d_in[10];
  const float* g2  = (const float*)d_in[11];
  const float* be2 = (const float*)d_in[12];
  const float* W3  = (const float*)d_in[13];
  const float* b3  = (const float*)d_in[14];
  const float* g3  = (const float*)d_in[15];
  const float* be3 = (const float*)d_in[16];
  const float* Wf  = (const float*)d_in[17];
  const float* bf  = (const float*)d_in[18];

  float* wsf = (float*)d_ws;
  int* idxb = (int*)d_ws;                                  // [8*2048*20] ints
  float* xcat = wsf + 327680;                              // [8][2048][512]
  float* norms = xcat + (size_t)NB * NP * 512;             // [8*2048]
  float* stats = norms + NB * NP;                          // [4][2][256]
  unsigned int* outenc = (unsigned int*)(stats + 2048);    // [8][1024]
  float* x4 = (float*)(outenc + NB * 1024);                // [8*2048][4]
  float* negd = x4 + (size_t)NB * NP * 4;                  // [2][2048][2048] (33.5 MB)
  float* featB = negd;                                     // aliases negd (different phase)

  hipMemsetAsync(stats, 0, 2048 * sizeof(float), stream);
  hipMemsetAsync(outenc, 0, NB * 1024 * sizeof(unsigned int), stream);

  const dim3 blk(256, 1, 1);
  const dim3 ggrid(32, 32, 2);

  pad_kernel<<<dim3(64), blk, 0, stream>>>(x, x4);

  // Layer 0 (C=3 -> 64, xcat cols [0,64))
  norms_kernel<4, 4><<<dim3(64), blk, 0, stream>>>(x4, norms);
  for (int cb = 0; cb < 4; ++cb) {
    knn_dist_kernel<4, 4, 1, 4><<<ggrid, blk, 0, stream>>>(x4, norms, negd, 2 * cb);
    knn_select_kernel<<<dim3(64), blk, 0, stream>>>(negd, idxb, 2 * cb);
  }
  conv_kernel<3, 4, 1, 64, 3><<<dim3(32, 2, 8), blk, 0, stream>>>(
      x, idxb, W0, b0, xcat, featB, stats, stats + 256);
  bnrelu_kernel<64><<<dim3(1024), blk, 0, stream>>>(xcat, featB, stats, stats + 256, g0, be0);

  // Layer 1 (64 -> 64, cols [64,128))
  norms_kernel<64, 512><<<dim3(64), blk, 0, stream>>>(xcat, norms);
  for (int cb = 0; cb < 4; ++cb) {
    knn_dist_kernel<64, 64, 1, 512><<<ggrid, blk, 0, stream>>>(xcat, norms, negd, 2 * cb);
    knn_select_kernel<<<dim3(64), blk, 0, stream>>>(negd, idxb, 2 * cb);
  }
  conv_kernel<64, 64, 1, 64, 512><<<dim3(32, 2, 8), blk, 0, stream>>>(
      xcat, idxb, W1, b1, xcat + 64, featB, stats + 512, stats + 768);
  bnrelu_kernel<64><<<dim3(1024), blk, 0, stream>>>(xcat + 64, featB, stats + 512, stats + 768, g1, be1);

  // Layer 2 (64 -> 128, cols [128,256))
  norms_kernel<64, 512><<<dim3(64), blk, 0, stream>>>(xcat + 64, norms);
  for (int cb = 0; cb < 4; ++cb) {
    knn_dist_kernel<64, 64, 1, 512><<<ggrid, blk, 0, stream>>>(xcat + 64, norms, negd, 2 * cb);
    knn_select_kernel<<<dim3(64), blk, 0, stream>>>(negd, idxb, 2 * cb);
  }
  conv_kernel<64, 64, 1, 128, 512><<<dim3(32, 4, 8), blk, 0, stream>>>(
      xcat + 64, idxb, W2, b2, xcat + 128, featB, stats + 1024, stats + 1280);
  bnrelu_kernel<128><<<dim3(2048), blk, 0, stream>>>(xcat + 128, featB, stats + 1024, stats + 1280, g2, be2);

  // Layer 3 (128 -> 256, cols [256,512))
  norms_kernel<128, 512><<<dim3(64), blk, 0, stream>>>(xcat + 128, norms);
  for (int cb = 0; cb < 4; ++cb) {
    knn_dist_kernel<128, 64, 2, 512><<<ggrid, blk, 0, stream>>>(xcat + 128, norms, negd, 2 * cb);
    knn_select_kernel<<<dim3(64), blk, 0, stream>>>(negd, idxb, 2 * cb);
  }
  conv_kernel<128, 64, 2, 256, 512><<<dim3(32, 8, 8), blk, 0, stream>>>(
      xcat + 128, idxb, W3, b3, xcat + 256, featB, stats + 1536, stats + 1792);
  bnrelu_kernel<256><<<dim3(4096), blk, 0, stream>>>(xcat + 256, featB, stats + 1536, stats + 1792, g3, be3);

  // Final 1x1 conv + global max pool
  final_kernel<<<dim3(32, 16, 8), blk, 0, stream>>>(xcat, Wf, outenc);
  decode_kernel<<<dim3(32), blk, 0, stream>>>(outenc, bf, (float*)d_out);
}

// Round 6
// 1802.006 us; speedup vs baseline: 2.8298x; 2.8298x over previous
//
#include <hip/hip_runtime.h>
#include <cstdint>
#include <cstddef>

// DGCNN forward, fp32. R6:
//  - knn_select v2: one wave per row, 32 vals/lane in regs (coalesced float4),
//    20x {shfl-max reduce, ballot lowest-lane winner, kill+rescan}. Grid 1024
//    blocks (R5's fatal flaw: 64 blocks = 0.25/CU). Stable ties: lane order ==
//    col-range order, in-lane first occurrence kept.
//  - knn_dist unchanged (2-batch chunks into negd, 33 KB LDS, 2048 blocks).
//  - conv: conv3 restages W1T per (k,cc) -> 32 KB LDS (4 blocks/CU);
//    conv0/conv1 k-split x4 (grid 1024); bnrelu maxes over splits.
//  - feat split buffers alias negd (disjoint phases).

constexpr int NB = 8;
constexpr int NP = 2048;
constexpr int KK = 20;

#define FMA16(AV, BV, ACC)                                          \
  {                                                                 \
    const float _a[4] = {AV.x, AV.y, AV.z, AV.w};                   \
    const float _b[4] = {BV.x, BV.y, BV.z, BV.w};                   \
    _Pragma("unroll")                                               \
    for (int _e = 0; _e < 4; ++_e) {                                \
      _Pragma("unroll")                                             \
      for (int _f = 0; _f < 4; ++_f)                                \
        ACC[_e][_f] = fmaf(_a[_e], _b[_f], ACC[_e][_f]);            \
    }                                                               \
  }

// ---------------- pad x -> x4 ----------------
__global__ __launch_bounds__(256) void pad_kernel(const float* __restrict__ x,
                                                  float* __restrict__ x4) {
  const int p = blockIdx.x * 256 + threadIdx.x;  // 16384 points
  float4 v;
  v.x = x[p * 3 + 0]; v.y = x[p * 3 + 1]; v.z = x[p * 3 + 2]; v.w = 0.f;
  *reinterpret_cast<float4*>(x4 + (size_t)p * 4) = v;
}

// ---------------- norms ----------------
template<int C, int RS>
__global__ __launch_bounds__(256) void norms_kernel(const float* __restrict__ X,
                                                    float* __restrict__ out) {
  const int g = blockIdx.x * 256 + threadIdx.x;  // 0 .. NB*NP-1
  const float* p = X + (size_t)g * RS;
  float s = 0.f;
#pragma unroll
  for (int c = 0; c < C; ++c) s = fmaf(p[c], p[c], s);
  out[g] = s;
}

// ---------------- knn distances: pure tiled Gram -> negd ----------------
template<int C, int CHUNK, int NCH, int RS>
__global__ __launch_bounds__(256) void knn_dist_kernel(const float* __restrict__ X,
    const float* __restrict__ norms, float* __restrict__ negd, int bbase) {
  constexpr bool SMALL = (CHUNK == 4);
  constexpr int XJ = SMALL ? 256 : 4096;
  constexpr int NIO = SMALL ? 512 : 8192;
  __shared__ float sb[NIO + 128];

  const int t = threadIdx.x, lane = t & 63, wid = t >> 6, tr = t & 15, tc = t >> 4;
  const int z = blockIdx.z, b = bbase + z;
  const int i0 = blockIdx.x * 64, j0 = blockIdx.y * 64;

  if (t < 64) sb[NIO + t] = norms[b * NP + i0 + t];
  else if (t < 128) sb[NIO + t] = norms[b * NP + j0 + (t - 64)];

  float acc[4][4] = {};
#pragma unroll
  for (int cc = 0; cc < NCH; ++cc) {
    __syncthreads();
    if constexpr (SMALL) {
      const int c = t >> 6, row = t & 63;
      sb[c * 64 + row] = X[(size_t)(b * NP + i0 + row) * RS + c];
      sb[XJ + c * 64 + row] = X[(size_t)(b * NP + j0 + row) * RS + c];
    } else {
#pragma unroll
      for (int i = 0; i < CHUNK / 16; ++i) {
        const int q = wid + i * 4;
        const float4 v = *reinterpret_cast<const float4*>(
            X + (size_t)(b * NP + i0 + lane) * RS + cc * CHUNK + q * 4);
        sb[(q * 4 + 0) * 64 + lane] = v.x;
        sb[(q * 4 + 1) * 64 + lane] = v.y;
        sb[(q * 4 + 2) * 64 + lane] = v.z;
        sb[(q * 4 + 3) * 64 + lane] = v.w;
        const float4 u = *reinterpret_cast<const float4*>(
            X + (size_t)(b * NP + j0 + lane) * RS + cc * CHUNK + q * 4);
        sb[XJ + (q * 4 + 0) * 64 + lane] = u.x;
        sb[XJ + (q * 4 + 1) * 64 + lane] = u.y;
        sb[XJ + (q * 4 + 2) * 64 + lane] = u.z;
        sb[XJ + (q * 4 + 3) * 64 + lane] = u.w;
      }
    }
    __syncthreads();
#pragma unroll
    for (int c = 0; c < CHUNK; ++c) {
      const float4 a = *reinterpret_cast<const float4*>(sb + c * 64 + tr * 4);
      const float4 bb = *reinterpret_cast<const float4*>(sb + XJ + c * 64 + tc * 4);
      FMA16(a, bb, acc);
    }
  }

  // negd = 2*dot - |xi|^2 - |xj|^2
#pragma unroll
  for (int e = 0; e < 4; ++e) {
    const int row = tr * 4 + e;
    const float ni = sb[NIO + row];
    float4 nd;
    nd.x = 2.f * acc[e][0] - ni - sb[NIO + 64 + tc * 4 + 0];
    nd.y = 2.f * acc[e][1] - ni - sb[NIO + 64 + tc * 4 + 1];
    nd.z = 2.f * acc[e][2] - ni - sb[NIO + 64 + tc * 4 + 2];
    nd.w = 2.f * acc[e][3] - ni - sb[NIO + 64 + tc * 4 + 3];
    *reinterpret_cast<float4*>(negd + ((size_t)z * NP + i0 + row) * NP + j0 + tc * 4) = nd;
  }
}

// ---------------- knn select v2: one wave per row ----------------
// Lane l holds cols [l*32, l*32+32) in regs. 20 rounds: wave-max reduce, ballot
// lowest winning lane (== lowest col range; stable), winner emits + kills + rescans.
__global__ __launch_bounds__(256) void knn_select_kernel(const float* __restrict__ negd,
    int* __restrict__ idxout, int bbase) {
  const int t = threadIdx.x, lane = t & 63, w = t >> 6;
  const int rloc = blockIdx.x * 4 + w;  // 0..4095 within 2-batch chunk
  const float* rowp = negd + (size_t)rloc * NP + lane * 32;

  float v[32];
#pragma unroll
  for (int m = 0; m < 8; ++m) {
    const float4 d = *reinterpret_cast<const float4*>(rowp + m * 4);
    v[m * 4 + 0] = d.x; v[m * 4 + 1] = d.y; v[m * 4 + 2] = d.z; v[m * 4 + 3] = d.w;
  }

  // per-lane max, first occurrence on ties (ascending scan, strict >)
  float lm = v[0]; int lp = 0;
#pragma unroll
  for (int e = 1; e < 32; ++e)
    if (v[e] > lm) { lm = v[e]; lp = e; }

  int* op = idxout + (size_t)(bbase * NP + rloc) * KK;
  for (int r = 0; r < KK; ++r) {
    float wm = lm;
#pragma unroll
    for (int o = 1; o < 64; o <<= 1) wm = fmaxf(wm, __shfl_xor(wm, o));
    const unsigned long long bal = __ballot(lm == wm);
    const int wl = __ffsll(bal) - 1;
    if (lane == wl) {
      op[r] = lane * 32 + lp;
#pragma unroll
      for (int e = 0; e < 32; ++e)
        if (e == lp) v[e] = -__builtin_inff();
      lm = v[0]; lp = 0;
#pragma unroll
      for (int e = 1; e < 32; ++e)
        if (v[e] > lm) { lm = v[e]; lp = e; }
    }
  }
}

// ---------------- edge conv (k-split x KS via blockIdx.y) ----------------
// CHUNK==64 layout: W chunk [0,4096) | A chunk [4096,8192)  -> 32 KB, 4 blocks/CU.
// W1T restaged per (k,cc) when NCH==2, once (k==kbeg) when NCH==1.
template<int C, int CHUNK, int NCH, int O, int RSIN, int KS>
__global__ __launch_bounds__(256) void conv_kernel(const float* __restrict__ X,
    const int* __restrict__ nbr, const float* __restrict__ W,
    const float* __restrict__ bias, float* __restrict__ outf,
    float* __restrict__ outfB, float* __restrict__ outfC, float* __restrict__ outfD,
    float* __restrict__ ssum, float* __restrict__ ssq) {
  constexpr bool SMALL = (CHUNK == 4);
  constexpr int AB = SMALL ? 2048 : 4096;  // A region base
  constexpr int SBF = SMALL ? 2304 : 8192;
  __shared__ float sb[SBF];
  constexpr int WS = 2 * C;
  constexpr int OB = O / 64;
  constexpr int KLEN = KK / KS;

  const int t = threadIdx.x, lane = t & 63, wid = t >> 6, tr = t & 15, tc = t >> 4;
  const int b = blockIdx.z, n0 = blockIdx.x * 64;
  const int oy = blockIdx.y % OB, ks = blockIdx.y / OB;
  const int o0 = oy * 64;
  const int kbeg = ks * KLEN, kend = kbeg + KLEN;

  float T[4][4];
  {
    float acc[4][4] = {};
#pragma unroll
    for (int cc = 0; cc < NCH; ++cc) {
      __syncthreads();
      if constexpr (SMALL) {
        const int c = t >> 6, row = t & 63;
        sb[AB + c * 64 + row] = (c < C) ? X[(size_t)(b * NP + n0 + row) * RSIN + c] : 0.f;
        sb[c * 64 + row] = (c < C) ? (W[(o0 + row) * WS + C + c] - W[(o0 + row) * WS + c]) : 0.f;
      } else {
#pragma unroll
        for (int i = 0; i < CHUNK / 16; ++i) {
          const int q = wid + i * 4;
          const float4 v = *reinterpret_cast<const float4*>(
              X + (size_t)(b * NP + n0 + lane) * RSIN + cc * CHUNK + q * 4);
          sb[AB + (q * 4 + 0) * 64 + lane] = v.x;
          sb[AB + (q * 4 + 1) * 64 + lane] = v.y;
          sb[AB + (q * 4 + 2) * 64 + lane] = v.z;
          sb[AB + (q * 4 + 3) * 64 + lane] = v.w;
          const float4 w1 = *reinterpret_cast<const float4*>(
              W + (size_t)(o0 + lane) * WS + cc * CHUNK + q * 4);
          const float4 w2 = *reinterpret_cast<const float4*>(
              W + (size_t)(o0 + lane) * WS + C + cc * CHUNK + q * 4);
          sb[(q * 4 + 0) * 64 + lane] = w2.x - w1.x;
          sb[(q * 4 + 1) * 64 + lane] = w2.y - w1.y;
          sb[(q * 4 + 2) * 64 + lane] = w2.z - w1.z;
          sb[(q * 4 + 3) * 64 + lane] = w2.w - w1.w;
        }
      }
      __syncthreads();
#pragma unroll
      for (int c = 0; c < CHUNK; ++c) {
        const float4 a = *reinterpret_cast<const float4*>(sb + AB + c * 64 + tr * 4);
        const float4 bb = *reinterpret_cast<const float4*>(sb + c * 64 + tc * 4);
        FMA16(a, bb, acc);
      }
    }
    const float4 bv = *reinterpret_cast<const float4*>(bias + o0 + tc * 4);
    const float bva[4] = {bv.x, bv.y, bv.z, bv.w};
#pragma unroll
    for (int e = 0; e < 4; ++e) {
#pragma unroll
      for (int f = 0; f < 4; ++f) T[e][f] = acc[e][f] + bva[f];
    }
  }

  if constexpr (SMALL) {
    // stage W1T once (tiny)
    __syncthreads();
    const int c = t >> 6, row = t & 63;
    sb[c * 64 + row] = (c < C) ? W[(o0 + row) * WS + c] : 0.f;
  }

  float mx[4][4], sm[4][4], s2[4][4];
#pragma unroll
  for (int e = 0; e < 4; ++e) {
#pragma unroll
    for (int f = 0; f < 4; ++f) { mx[e][f] = -__builtin_inff(); sm[e][f] = 0.f; s2[e][f] = 0.f; }
  }

  for (int k = kbeg; k < kend; ++k) {
    const int jr = nbr[(size_t)(b * NP + n0 + lane) * KK + k];
    float acc[4][4] = {};
#pragma unroll
    for (int cc = 0; cc < NCH; ++cc) {
      __syncthreads();
      if constexpr (SMALL) {
        const int c = t >> 6, row = t & 63;
        const int jrr = nbr[(size_t)(b * NP + n0 + row) * KK + k];
        sb[AB + c * 64 + row] = (c < C) ? X[(size_t)(b * NP + jrr) * RSIN + c] : 0.f;
      } else {
        // restage W1 chunk cc (NCH==2: every (k,cc); NCH==1: first k only)
        if (NCH == 2 || k == kbeg) {
#pragma unroll
          for (int i = 0; i < CHUNK / 16; ++i) {
            const int q = wid + i * 4;
            const float4 w1 = *reinterpret_cast<const float4*>(
                W + (size_t)(o0 + lane) * WS + cc * CHUNK + q * 4);
            sb[(q * 4 + 0) * 64 + lane] = w1.x;
            sb[(q * 4 + 1) * 64 + lane] = w1.y;
            sb[(q * 4 + 2) * 64 + lane] = w1.z;
            sb[(q * 4 + 3) * 64 + lane] = w1.w;
          }
        }
#pragma unroll
        for (int i = 0; i < CHUNK / 16; ++i) {
          const int q = wid + i * 4;
          const float4 v = *reinterpret_cast<const float4*>(
              X + (size_t)(b * NP + jr) * RSIN + cc * CHUNK + q * 4);
          sb[AB + (q * 4 + 0) * 64 + lane] = v.x;
          sb[AB + (q * 4 + 1) * 64 + lane] = v.y;
          sb[AB + (q * 4 + 2) * 64 + lane] = v.z;
          sb[AB + (q * 4 + 3) * 64 + lane] = v.w;
        }
      }
      __syncthreads();
#pragma unroll
      for (int c = 0; c < CHUNK; ++c) {
        const float4 a = *reinterpret_cast<const float4*>(sb + AB + c * 64 + tr * 4);
        const float4 bb = *reinterpret_cast<const float4*>(sb + c * 64 + tc * 4);
        FMA16(a, bb, acc);
      }
    }
#pragma unroll
    for (int e = 0; e < 4; ++e) {
#pragma unroll
      for (int f = 0; f < 4; ++f) {
        const float h = acc[e][f] + T[e][f];
        mx[e][f] = fmaxf(mx[e][f], h);
        sm[e][f] += h;
        s2[e][f] = fmaf(h, h, s2[e][f]);
      }
    }
  }

  // write max-over-k-split (pre-BN)
  {
    float* dst; int dstride;
    if (ks == 0) { dst = outf; dstride = 512; }
    else { dst = (ks == 1) ? outfB : ((ks == 2) ? outfC : outfD); dstride = O; }
#pragma unroll
    for (int e = 0; e < 4; ++e) {
      float4 o4;
      o4.x = mx[e][0]; o4.y = mx[e][1]; o4.z = mx[e][2]; o4.w = mx[e][3];
      *reinterpret_cast<float4*>(dst + (size_t)(b * NP + n0 + tr * 4 + e) * dstride + o0 + tc * 4) = o4;
    }
  }

  __syncthreads();
#pragma unroll
  for (int f = 0; f < 4; ++f) {
    sb[tr * 64 + tc * 4 + f] = sm[0][f] + sm[1][f] + sm[2][f] + sm[3][f];
    sb[1024 + tr * 64 + tc * 4 + f] = s2[0][f] + s2[1][f] + s2[2][f] + s2[3][f];
  }
  __syncthreads();
  if (t < 64) {
    float S = 0.f, Q = 0.f;
#pragma unroll
    for (int r = 0; r < 16; ++r) { S += sb[r * 64 + t]; Q += sb[1024 + r * 64 + t]; }
    atomicAdd(ssum + o0 + t, S);
    atomicAdd(ssq + o0 + t, Q);
  }
}

// ---------------- bn + leaky relu (merge NS k-splits, post-max) ----------------
template<int O, int NS>
__global__ __launch_bounds__(256) void bnrelu_kernel(float* __restrict__ feat,
    const float* __restrict__ fB, const float* __restrict__ fC,
    const float* __restrict__ fD,
    const float* __restrict__ ssum, const float* __restrict__ ssq,
    const float* __restrict__ g, const float* __restrict__ be) {
  constexpr float INV = 1.0f / 327680.0f;  // B*N*K
  const int t4 = blockIdx.x * 256 + threadIdx.x;
  const int e0 = t4 * 4;
  const int r = e0 / O, c = e0 % O;
  float4 h = *reinterpret_cast<float4*>(feat + (size_t)r * 512 + c);
  float hv[4] = {h.x, h.y, h.z, h.w};
  {
    const float4 h2 = *reinterpret_cast<const float4*>(fB + (size_t)r * O + c);
    hv[0] = fmaxf(hv[0], h2.x); hv[1] = fmaxf(hv[1], h2.y);
    hv[2] = fmaxf(hv[2], h2.z); hv[3] = fmaxf(hv[3], h2.w);
  }
  if (NS >= 4) {
    const float4 h3 = *reinterpret_cast<const float4*>(fC + (size_t)r * O + c);
    const float4 h4 = *reinterpret_cast<const float4*>(fD + (size_t)r * O + c);
    hv[0] = fmaxf(fmaxf(hv[0], h3.x), h4.x);
    hv[1] = fmaxf(fmaxf(hv[1], h3.y), h4.y);
    hv[2] = fmaxf(fmaxf(hv[2], h3.z), h4.z);
    hv[3] = fmaxf(fmaxf(hv[3], h3.w), h4.w);
  }
#pragma unroll
  for (int j = 0; j < 4; ++j) {
    const int col = c + j;
    const float m = ssum[col] * INV;
    const float v = ssq[col] * INV - m * m;
    const float sc = g[col] / sqrtf(v + 1e-5f);
    const float val = (hv[j] - m) * sc + be[col];
    hv[j] = (val >= 0.f) ? val : 0.2f * val;
  }
  h.x = hv[0]; h.y = hv[1]; h.z = hv[2]; h.w = hv[3];
  *reinterpret_cast<float4*>(feat + (size_t)r * 512 + c) = h;
}

// ---------------- final conv + global max pool ----------------
__global__ __launch_bounds__(256) void final_kernel(const float* __restrict__ xcat,
    const float* __restrict__ Wf, unsigned int* __restrict__ outenc) {
  __shared__ float sb[9216];  // AT 4096 | WfT 4096 | mred 1024
  const int t = threadIdx.x, lane = t & 63, wid = t >> 6, tr = t & 15, tc = t >> 4;
  const int b = blockIdx.z, n0 = blockIdx.x * 64, o0 = blockIdx.y * 64;
  float acc[4][4] = {};
  for (int cc = 0; cc < 8; ++cc) {
    __syncthreads();
#pragma unroll
    for (int i = 0; i < 4; ++i) {
      const int q = wid + i * 4;
      const float4 v = *reinterpret_cast<const float4*>(
          xcat + (size_t)(b * NP + n0 + lane) * 512 + cc * 64 + q * 4);
      sb[(q * 4 + 0) * 64 + lane] = v.x;
      sb[(q * 4 + 1) * 64 + lane] = v.y;
      sb[(q * 4 + 2) * 64 + lane] = v.z;
      sb[(q * 4 + 3) * 64 + lane] = v.w;
      const float4 w4 = *reinterpret_cast<const float4*>(
          Wf + (size_t)(o0 + lane) * 512 + cc * 64 + q * 4);
      sb[4096 + (q * 4 + 0) * 64 + lane] = w4.x;
      sb[4096 + (q * 4 + 1) * 64 + lane] = w4.y;
      sb[4096 + (q * 4 + 2) * 64 + lane] = w4.z;
      sb[4096 + (q * 4 + 3) * 64 + lane] = w4.w;
    }
    __syncthreads();
#pragma unroll
    for (int c = 0; c < 64; ++c) {
      const float4 a = *reinterpret_cast<const float4*>(sb + c * 64 + tr * 4);
      const float4 bb = *reinterpret_cast<const float4*>(sb + 4096 + c * 64 + tc * 4);
      FMA16(a, bb, acc);
    }
  }
  float m4[4];
#pragma unroll
  for (int f = 0; f < 4; ++f)
    m4[f] = fmaxf(fmaxf(acc[0][f], acc[1][f]), fmaxf(acc[2][f], acc[3][f]));
  __syncthreads();
#pragma unroll
  for (int f = 0; f < 4; ++f) sb[8192 + tr * 64 + tc * 4 + f] = m4[f];
  __syncthreads();
  if (t < 64) {
    float M = -__builtin_inff();
#pragma unroll
    for (int r = 0; r < 16; ++r) M = fmaxf(M, sb[8192 + r * 64 + t]);
    const unsigned ubits = __float_as_uint(M);
    const unsigned key = (ubits & 0x80000000u) ? ~ubits : (ubits | 0x80000000u);
    atomicMax(outenc + b * 1024 + o0 + t, key);
  }
}

__global__ __launch_bounds__(256) void decode_kernel(const unsigned int* __restrict__ enc,
    const float* __restrict__ bf, float* __restrict__ out) {
  const int gid = blockIdx.x * 256 + threadIdx.x;  // 8192
  const unsigned key = enc[gid];
  const unsigned ubits = (key & 0x80000000u) ? (key & 0x7fffffffu) : ~key;
  out[gid] = __uint_as_float(ubits) + bf[gid & 1023];
}

// ---------------- launch ----------------
extern "C" void kernel_launch(void* const* d_in, const int* in_sizes, int n_in,
                              void* d_out, int out_size, void* d_ws, size_t ws_size,
                              hipStream_t stream) {
  (void)in_sizes; (void)n_in; (void)out_size; (void)ws_size;
  const float* x   = (const float*)d_in[0];
  const float* W0  = (const float*)d_in[1];
  const float* b0  = (const float*)d_in[2];
  const float* g0  = (const float*)d_in[3];
  const float* be0 = (const float*)d_in[4];
  const float* W1  = (const float*)d_in[5];
  const float* b1  = (const float*)d_in[6];
  const float* g1  = (const float*)d_in[7];
  const float* be1 = (const float*)d_in[8];
  const float* W2  = (const float*)d_in[9];
  const float* b2  = (const float*)d_in[10];
  const float* g2  = (const float*)d_in[11];
  const float* be2 = (const float*)d_in[12];
  const float* W3  = (const float*)d_in[13];
  const float* b3  = (const float*)d_in[14];
  const float* g3  = (const float*)d_in[15];
  const float* be3 = (const float*)d_in[16];
  const float* Wf  = (const float*)d_in[17];
  const float* bf  = (const float*)d_in[18];

  float* wsf = (float*)d_ws;
  int* idxb = (int*)d_ws;                                  // [8*2048*20] ints
  float* xcat = wsf + 327680;                              // [8][2048][512]
  float* norms = xcat + (size_t)NB * NP * 512;             // [8*2048]
  float* stats = norms + NB * NP;                          // [4][2][256]
  unsigned int* outenc = (unsigned int*)(stats + 2048);    // [8][1024]
  float* x4 = (float*)(outenc + NB * 1024);                // [8*2048][4]
  float* negd = x4 + (size_t)NB * NP * 4;                  // [2][2048][2048] (33.5 MB)
  // feat split buffers alias negd (knn phase vs conv phase are disjoint)
  float* featB = negd;                                     // up to [8*2048*256]
  float* featC = negd + (size_t)NB * NP * 256;             // [8*2048*64]
  float* featD = featC + (size_t)NB * NP * 64;             // [8*2048*64]

  hipMemsetAsync(stats, 0, 2048 * sizeof(float), stream);
  hipMemsetAsync(outenc, 0, NB * 1024 * sizeof(unsigned int), stream);

  const dim3 blk(256, 1, 1);
  const dim3 ggrid(32, 32, 2);
  const dim3 sgrid(1024, 1, 1);

  pad_kernel<<<dim3(64), blk, 0, stream>>>(x, x4);

  // Layer 0 (C=3 -> 64, xcat cols [0,64))
  norms_kernel<4, 4><<<dim3(64), blk, 0, stream>>>(x4, norms);
  for (int cb = 0; cb < 4; ++cb) {
    knn_dist_kernel<4, 4, 1, 4><<<ggrid, blk, 0, stream>>>(x4, norms, negd, 2 * cb);
    knn_select_kernel<<<sgrid, blk, 0, stream>>>(negd, idxb, 2 * cb);
  }
  conv_kernel<3, 4, 1, 64, 3, 4><<<dim3(32, 4, 8), blk, 0, stream>>>(
      x, idxb, W0, b0, xcat, featB, featC, featD, stats, stats + 256);
  bnrelu_kernel<64, 4><<<dim3(1024), blk, 0, stream>>>(
      xcat, featB, featC, featD, stats, stats + 256, g0, be0);

  // Layer 1 (64 -> 64, cols [64,128))
  norms_kernel<64, 512><<<dim3(64), blk, 0, stream>>>(xcat, norms);
  for (int cb = 0; cb < 4; ++cb) {
    knn_dist_kernel<64, 64, 1, 512><<<ggrid, blk, 0, stream>>>(xcat, norms, negd, 2 * cb);
    knn_select_kernel<<<sgrid, blk, 0, stream>>>(negd, idxb, 2 * cb);
  }
  conv_kernel<64, 64, 1, 64, 512, 4><<<dim3(32, 4, 8), blk, 0, stream>>>(
      xcat, idxb, W1, b1, xcat + 64, featB, featC, featD, stats + 512, stats + 768);
  bnrelu_kernel<64, 4><<<dim3(1024), blk, 0, stream>>>(
      xcat + 64, featB, featC, featD, stats + 512, stats + 768, g1, be1);

  // Layer 2 (64 -> 128, cols [128,256))
  norms_kernel<64, 512><<<dim3(64), blk, 0, stream>>>(xcat + 64, norms);
  for (int cb = 0; cb < 4; ++cb) {
    knn_dist_kernel<64, 64, 1, 512><<<ggrid, blk, 0, stream>>>(xcat + 64, norms, negd, 2 * cb);
    knn_select_kernel<<<sgrid, blk, 0, stream>>>(negd, idxb, 2 * cb);
  }
  conv_kernel<64, 64, 1, 128, 512, 2><<<dim3(32, 4, 8), blk, 0, stream>>>(
      xcat + 64, idxb, W2, b2, xcat + 128, featB, featC, featD, stats + 1024, stats + 1280);
  bnrelu_kernel<128, 2><<<dim3(2048), blk, 0, stream>>>(
      xcat + 128, featB, featC, featD, stats + 1024, stats + 1280, g2, be2);

  // Layer 3 (128 -> 256, cols [256,512))
  norms_kernel<128, 512><<<dim3(64), blk, 0, stream>>>(xcat + 128, norms);
  for (int cb = 0; cb < 4; ++cb) {
    knn_dist_kernel<128, 64, 2, 512><<<ggrid, blk, 0, stream>>>(xcat + 128, norms, negd, 2 * cb);
    knn_select_kernel<<<sgrid, blk, 0, stream>>>(negd, idxb, 2 * cb);
  }
  conv_kernel<128, 64, 2, 256, 512, 2><<<dim3(32, 8, 8), blk, 0, stream>>>(
      xcat + 128, idxb, W3, b3, xcat + 256, featB, featC, featD, stats + 1536, stats + 1792);
  bnrelu_kernel<256, 2><<<dim3(4096), blk, 0, stream>>>(
      xcat + 256, featB, featC, featD, stats + 1536, stats + 1792, g3, be3);

  // Final 1x1 conv + global max pool
  final_kernel<<<dim3(32, 16, 8), blk, 0, stream>>>(xcat, Wf, outenc);
  decode_kernel<<<dim3(32), blk, 0, stream>>>(outenc, bf, (float*)d_out);
}

// Round 7
// 1376.757 us; speedup vs baseline: 3.7039x; 1.3089x over previous
//
#include <hip/hip_runtime.h>
#include <cstdint>
#include <cstddef>

// DGCNN forward. R7: all big GEMMs (dist l>=1, conv l>=1, final) moved to
// v_mfma_f32_32x32x16_bf16 with split-bf16 (v = hi + lo planes; 3 MFMA:
// ah*bh + ah*bl + al*bh -> ~2^-14 relative accuracy, fp32 accumulate).
// Features live as two bf16 planes xh/xl [16384][512] (layer slices at cols
// 0/64/128/256); bnrelu writes them; norms/dist/conv/final consume them.
// LDS uses fragment-contiguous [k8][row][8] layout -> conflict-free b128.
// L0 (C=3) stays on the fp32 vector path. Select kernel unchanged from R6.

constexpr int NB = 8;
constexpr int NP = 2048;
constexpr int KK = 20;

typedef short bf16x8 __attribute__((ext_vector_type(8)));
typedef float f32x16 __attribute__((ext_vector_type(16)));

__device__ __forceinline__ f32x16 MF(bf16x8 a, bf16x8 b, f32x16 c) {
  return __builtin_amdgcn_mfma_f32_32x32x16_bf16(a, b, c, 0, 0, 0);
}
__device__ __forceinline__ unsigned short bfh(float f) {
  return (unsigned short)(__float_as_uint(f) >> 16);  // truncating bf16
}
__device__ __forceinline__ float bff(unsigned short u) {
  return __uint_as_float(((unsigned)u) << 16);
}
__device__ __forceinline__ void split2(float v, unsigned short& h, unsigned short& l) {
  h = bfh(v); l = bfh(v - bff(h));
}
__device__ __forceinline__ void stage16(unsigned short* dst, const unsigned short* src) {
  *reinterpret_cast<uint4*>(dst) = *reinterpret_cast<const uint4*>(src);
}

#define FMA16(AV, BV, ACC)                                          \
  {                                                                 \
    const float _a[4] = {AV.x, AV.y, AV.z, AV.w};                   \
    const float _b[4] = {BV.x, BV.y, BV.z, BV.w};                   \
    _Pragma("unroll")                                               \
    for (int _e = 0; _e < 4; ++_e) {                                \
      _Pragma("unroll")                                             \
      for (int _f = 0; _f < 4; ++_f)                                \
        ACC[_e][_f] = fmaf(_a[_e], _b[_f], ACC[_e][_f]);            \
    }                                                               \
  }

// ---------------- pad x -> x4 ----------------
__global__ __launch_bounds__(256) void pad_kernel(const float* __restrict__ x,
                                                  float* __restrict__ x4) {
  const int p = blockIdx.x * 256 + threadIdx.x;
  float4 v;
  v.x = x[p * 3 + 0]; v.y = x[p * 3 + 1]; v.z = x[p * 3 + 2]; v.w = 0.f;
  *reinterpret_cast<float4*>(x4 + (size_t)p * 4) = v;
}

// ---------------- weight splits ----------------
template<int O, int C>
__global__ __launch_bounds__(256) void wsplit_conv(const float* __restrict__ W,
    unsigned short* __restrict__ w1h, unsigned short* __restrict__ w1l,
    unsigned short* __restrict__ wdh, unsigned short* __restrict__ wdl) {
  const int id = blockIdx.x * 256 + threadIdx.x;  // O*C
  const int o = id / C, c = id % C;
  const float w1 = W[o * 2 * C + c];
  const float w2 = W[o * 2 * C + C + c];
  unsigned short h, l;
  split2(w1, h, l); w1h[id] = h; w1l[id] = l;
  split2(w2 - w1, h, l); wdh[id] = h; wdl[id] = l;
}

__global__ __launch_bounds__(256) void wsplit_final(const float* __restrict__ Wf,
    unsigned short* __restrict__ wfh, unsigned short* __restrict__ wfl) {
  const int id = blockIdx.x * 256 + threadIdx.x;  // 1024*512
  unsigned short h, l;
  split2(Wf[id], h, l); wfh[id] = h; wfl[id] = l;
}

// ---------------- norms ----------------
__global__ __launch_bounds__(256) void norms4_kernel(const float* __restrict__ X,
                                                     float* __restrict__ out) {
  const int g = blockIdx.x * 256 + threadIdx.x;
  const float4 v = *reinterpret_cast<const float4*>(X + (size_t)g * 4);
  out[g] = v.x * v.x + v.y * v.y + v.z * v.z;
}

template<int C>
__global__ __launch_bounds__(256) void norms_planes(const unsigned short* __restrict__ xh,
    const unsigned short* __restrict__ xl, int colbase, float* __restrict__ out) {
  const int g = blockIdx.x * 256 + threadIdx.x;
  const size_t base = (size_t)g * 512 + colbase;
  float s = 0.f;
#pragma unroll
  for (int k8 = 0; k8 < C / 8; ++k8) {
    const uint4 uh = *reinterpret_cast<const uint4*>(xh + base + k8 * 8);
    const uint4 ul = *reinterpret_cast<const uint4*>(xl + base + k8 * 8);
    const unsigned hs[4] = {uh.x, uh.y, uh.z, uh.w};
    const unsigned ls[4] = {ul.x, ul.y, ul.z, ul.w};
#pragma unroll
    for (int q = 0; q < 4; ++q) {
      const float v0 = __uint_as_float(hs[q] << 16) + __uint_as_float(ls[q] << 16);
      const float v1 = __uint_as_float(hs[q] & 0xffff0000u) + __uint_as_float(ls[q] & 0xffff0000u);
      s = fmaf(v0, v0, s);
      s = fmaf(v1, v1, s);
    }
  }
  out[g] = s;
}

// ---------------- dist L0 (C=3, fp32 vector) ----------------
__global__ __launch_bounds__(256) void dist0_kernel(const float* __restrict__ X4,
    const float* __restrict__ norms, float* __restrict__ negd, int bbase) {
  __shared__ float sb[640];
  const int t = threadIdx.x, tr = t & 15, tcq = t >> 4;
  const int z = blockIdx.z, b = bbase + z;
  const int i0 = blockIdx.x * 64, j0 = blockIdx.y * 64;
  const int c4 = t >> 6, row = t & 63;
  if (t < 64) sb[512 + t] = norms[b * NP + i0 + t];
  else if (t < 128) sb[512 + t] = norms[b * NP + j0 + (t - 64)];
  sb[c4 * 64 + row] = X4[(size_t)(b * NP + i0 + row) * 4 + c4];
  sb[256 + c4 * 64 + row] = X4[(size_t)(b * NP + j0 + row) * 4 + c4];
  __syncthreads();
  float acc[4][4] = {};
#pragma unroll
  for (int c = 0; c < 4; ++c) {
    const float4 a = *reinterpret_cast<const float4*>(sb + c * 64 + tr * 4);
    const float4 bb = *reinterpret_cast<const float4*>(sb + 256 + c * 64 + tcq * 4);
    FMA16(a, bb, acc);
  }
#pragma unroll
  for (int e = 0; e < 4; ++e) {
    const int rowi = tr * 4 + e;
    const float ni = sb[512 + rowi];
    float4 nd;
    nd.x = 2.f * acc[e][0] - ni - sb[576 + tcq * 4 + 0];
    nd.y = 2.f * acc[e][1] - ni - sb[576 + tcq * 4 + 1];
    nd.z = 2.f * acc[e][2] - ni - sb[576 + tcq * 4 + 2];
    nd.w = 2.f * acc[e][3] - ni - sb[576 + tcq * 4 + 3];
    *reinterpret_cast<float4*>(negd + ((size_t)z * NP + i0 + rowi) * NP + j0 + tcq * 4) = nd;
  }
}

// ---------------- dist MFMA (l>=1) ----------------
template<int C>
__global__ __launch_bounds__(256) void dist_mfma(const unsigned short* __restrict__ xh,
    const unsigned short* __restrict__ xl, int colbase,
    const float* __restrict__ norms, float* __restrict__ negd, int bbase) {
  constexpr int K8 = C / 8;
  __shared__ __align__(16) unsigned short sb[4 * K8 * 512];
  __shared__ float fn[128];
  unsigned short* sAh = sb;
  unsigned short* sAl = sb + K8 * 512;
  unsigned short* sBh = sb + 2 * K8 * 512;
  unsigned short* sBl = sb + 3 * K8 * 512;

  const int t = threadIdx.x, lane = t & 63, w = t >> 6;
  const int half = lane >> 5, l31 = lane & 31;
  const int rt = (w >> 1) * 32, tc = (w & 1) * 32;
  const int z = blockIdx.z, b = bbase + z;
  const int i0 = blockIdx.x * 64, j0 = blockIdx.y * 64;

  if (t < 64) fn[t] = norms[b * NP + i0 + t];
  else if (t < 128) fn[t] = norms[b * NP + j0 + (t - 64)];

  {
    const int r = t & 63;
    const size_t gi = ((size_t)(b * NP + i0 + r)) * 512 + colbase;
    const size_t gj = ((size_t)(b * NP + j0 + r)) * 512 + colbase;
#pragma unroll
    for (int i = 0; i < K8 / 4; ++i) {
      const int k8 = (t >> 6) + 4 * i;
      stage16(sAh + (k8 * 64 + r) * 8, xh + gi + k8 * 8);
      stage16(sAl + (k8 * 64 + r) * 8, xl + gi + k8 * 8);
      stage16(sBh + (k8 * 64 + r) * 8, xh + gj + k8 * 8);
      stage16(sBl + (k8 * 64 + r) * 8, xl + gj + k8 * 8);
    }
  }
  __syncthreads();

  f32x16 acc;
#pragma unroll
  for (int i = 0; i < 16; ++i) acc[i] = 0.f;
#pragma unroll
  for (int cc = 0; cc < K8 / 2; ++cc) {
    const int k8 = cc * 2 + half;
    const bf16x8 ah = *reinterpret_cast<const bf16x8*>(sAh + (k8 * 64 + rt + l31) * 8);
    const bf16x8 al = *reinterpret_cast<const bf16x8*>(sAl + (k8 * 64 + rt + l31) * 8);
    const bf16x8 bh = *reinterpret_cast<const bf16x8*>(sBh + (k8 * 64 + tc + l31) * 8);
    const bf16x8 bl = *reinterpret_cast<const bf16x8*>(sBl + (k8 * 64 + tc + l31) * 8);
    acc = MF(ah, bh, acc);
    acc = MF(ah, bl, acc);
    acc = MF(al, bh, acc);
  }

  const int col = tc + l31;
  const float nj = fn[64 + col];
#pragma unroll
  for (int i = 0; i < 16; ++i) {
    const int row = rt + (i & 3) + 8 * (i >> 2) + 4 * half;
    negd[((size_t)z * NP + i0 + row) * NP + j0 + col] = 2.f * acc[i] - fn[row] - nj;
  }
}

// ---------------- knn select (R6, unchanged) ----------------
__global__ __launch_bounds__(256) void knn_select_kernel(const float* __restrict__ negd,
    int* __restrict__ idxout, int bbase) {
  const int t = threadIdx.x, lane = t & 63, w = t >> 6;
  const int rloc = blockIdx.x * 4 + w;
  const float* rowp = negd + (size_t)rloc * NP + lane * 32;

  float v[32];
#pragma unroll
  for (int m = 0; m < 8; ++m) {
    const float4 d = *reinterpret_cast<const float4*>(rowp + m * 4);
    v[m * 4 + 0] = d.x; v[m * 4 + 1] = d.y; v[m * 4 + 2] = d.z; v[m * 4 + 3] = d.w;
  }
  float lm = v[0]; int lp = 0;
#pragma unroll
  for (int e = 1; e < 32; ++e)
    if (v[e] > lm) { lm = v[e]; lp = e; }

  int* op = idxout + (size_t)(bbase * NP + rloc) * KK;
  for (int r = 0; r < KK; ++r) {
    float wm = lm;
#pragma unroll
    for (int o = 1; o < 64; o <<= 1) wm = fmaxf(wm, __shfl_xor(wm, o));
    const unsigned long long bal = __ballot(lm == wm);
    const int wl = __ffsll(bal) - 1;
    if (lane == wl) {
      op[r] = lane * 32 + lp;
#pragma unroll
      for (int e = 0; e < 32; ++e)
        if (e == lp) v[e] = -__builtin_inff();
      lm = v[0]; lp = 0;
#pragma unroll
      for (int e = 1; e < 32; ++e)
        if (v[e] > lm) { lm = v[e]; lp = e; }
    }
  }
}

// ---------------- conv L0 (C=3, fp32 vector, KS=4) ----------------
__global__ __launch_bounds__(256) void conv0_kernel(const float* __restrict__ X,
    const int* __restrict__ nbr, const float* __restrict__ W,
    const float* __restrict__ bias,
    float* __restrict__ fA, float* __restrict__ fB, float* __restrict__ fC,
    float* __restrict__ fD, float* __restrict__ ssum, float* __restrict__ ssq) {
  __shared__ float sb[2304];  // W1 [0,256) | A [2048,2304) | stats alias [0,2048)
  const int t = threadIdx.x, tr = t & 15, tcq = t >> 4;
  const int b = blockIdx.z, n0 = blockIdx.x * 64;
  const int ks = blockIdx.y;
  const int c4 = t >> 6, row = t & 63;

  float T[4][4];
  {
    float acc[4][4] = {};
    sb[2048 + c4 * 64 + row] = (c4 < 3) ? X[(size_t)(b * NP + n0 + row) * 3 + c4] : 0.f;
    sb[c4 * 64 + row] = (c4 < 3) ? (W[row * 6 + 3 + c4] - W[row * 6 + c4]) : 0.f;
    __syncthreads();
#pragma unroll
    for (int c = 0; c < 4; ++c) {
      const float4 a = *reinterpret_cast<const float4*>(sb + 2048 + c * 64 + tr * 4);
      const float4 bb = *reinterpret_cast<const float4*>(sb + c * 64 + tcq * 4);
      FMA16(a, bb, acc);
    }
    const float4 bv = *reinterpret_cast<const float4*>(bias + tcq * 4);
    const float bva[4] = {bv.x, bv.y, bv.z, bv.w};
#pragma unroll
    for (int e = 0; e < 4; ++e) {
#pragma unroll
      for (int f = 0; f < 4; ++f) T[e][f] = acc[e][f] + bva[f];
    }
  }
  __syncthreads();
  sb[c4 * 64 + row] = (c4 < 3) ? W[row * 6 + c4] : 0.f;

  float mx[4][4], sm[4][4], s2[4][4];
#pragma unroll
  for (int e = 0; e < 4; ++e) {
#pragma unroll
    for (int f = 0; f < 4; ++f) { mx[e][f] = -__builtin_inff(); sm[e][f] = 0.f; s2[e][f] = 0.f; }
  }

  for (int k = ks * 5; k < ks * 5 + 5; ++k) {
    __syncthreads();
    const int jrr = nbr[(size_t)(b * NP + n0 + row) * KK + k];
    sb[2048 + c4 * 64 + row] = (c4 < 3) ? X[(size_t)(b * NP + jrr) * 3 + c4] : 0.f;
    __syncthreads();
    float acc[4][4] = {};
#pragma unroll
    for (int c = 0; c < 4; ++c) {
      const float4 a = *reinterpret_cast<const float4*>(sb + 2048 + c * 64 + tr * 4);
      const float4 bb = *reinterpret_cast<const float4*>(sb + c * 64 + tcq * 4);
      FMA16(a, bb, acc);
    }
#pragma unroll
    for (int e = 0; e < 4; ++e) {
#pragma unroll
      for (int f = 0; f < 4; ++f) {
        const float h = acc[e][f] + T[e][f];
        mx[e][f] = fmaxf(mx[e][f], h);
        sm[e][f] += h;
        s2[e][f] = fmaf(h, h, s2[e][f]);
      }
    }
  }

  float* dst = (ks == 0) ? fA : ((ks == 1) ? fB : ((ks == 2) ? fC : fD));
#pragma unroll
  for (int e = 0; e < 4; ++e) {
    float4 o4;
    o4.x = mx[e][0]; o4.y = mx[e][1]; o4.z = mx[e][2]; o4.w = mx[e][3];
    *reinterpret_cast<float4*>(dst + (size_t)(b * NP + n0 + tr * 4 + e) * 64 + tcq * 4) = o4;
  }
  __syncthreads();
#pragma unroll
  for (int f = 0; f < 4; ++f) {
    sb[tr * 64 + tcq * 4 + f] = sm[0][f] + sm[1][f] + sm[2][f] + sm[3][f];
    sb[1024 + tr * 64 + tcq * 4 + f] = s2[0][f] + s2[1][f] + s2[2][f] + s2[3][f];
  }
  __syncthreads();
  if (t < 64) {
    float S = 0.f, Q = 0.f;
#pragma unroll
    for (int r16 = 0; r16 < 16; ++r16) { S += sb[r16 * 64 + t]; Q += sb[1024 + r16 * 64 + t]; }
    atomicAdd(ssum + t, S);
    atomicAdd(ssq + t, Q);
  }
}

// ---------------- conv MFMA (l>=1) ----------------
template<int C, int O, int KS, bool HOIST>
__global__ __launch_bounds__(256) void conv_mfma(const unsigned short* __restrict__ xh,
    const unsigned short* __restrict__ xl, int colbase,
    const int* __restrict__ nbr,
    const unsigned short* __restrict__ w1h, const unsigned short* __restrict__ w1l,
    const unsigned short* __restrict__ wdh, const unsigned short* __restrict__ wdl,
    const float* __restrict__ bias,
    float* __restrict__ fA, float* __restrict__ fB, float* __restrict__ fC,
    float* __restrict__ fD,
    float* __restrict__ ssum, float* __restrict__ ssq) {
  constexpr int K8 = C / 8;
  constexpr int OB = O / 64;
  constexpr int KLEN = KK / KS;
  __shared__ __align__(16) unsigned short sb[4 * K8 * 512];
  unsigned short* sBh = sb;
  unsigned short* sBl = sb + K8 * 512;
  unsigned short* sAh = sb + 2 * K8 * 512;
  unsigned short* sAl = sb + 3 * K8 * 512;

  const int t = threadIdx.x, lane = t & 63, w = t >> 6;
  const int half = lane >> 5, l31 = lane & 31;
  const int rt = (w >> 1) * 32, tc = (w & 1) * 32;
  const int b = blockIdx.z, n0 = blockIdx.x * 64;
  const int oy = blockIdx.y % OB, ks = blockIdx.y / OB;
  const int o0 = oy * 64;
  const int r = t & 63, k80 = t >> 6;

  // phase 0: T = Wd*ctr + bias
  {
    const size_t gc = ((size_t)(b * NP + n0 + r)) * 512 + colbase;
    const size_t gw = (size_t)(o0 + r) * C;
#pragma unroll
    for (int i = 0; i < K8 / 4; ++i) {
      const int k8 = k80 + 4 * i;
      stage16(sAh + (k8 * 64 + r) * 8, xh + gc + k8 * 8);
      stage16(sAl + (k8 * 64 + r) * 8, xl + gc + k8 * 8);
      stage16(sBh + (k8 * 64 + r) * 8, wdh + gw + k8 * 8);
      stage16(sBl + (k8 * 64 + r) * 8, wdl + gw + k8 * 8);
    }
  }
  __syncthreads();
  f32x16 acc;
#pragma unroll
  for (int i = 0; i < 16; ++i) acc[i] = 0.f;
#pragma unroll
  for (int cc = 0; cc < K8 / 2; ++cc) {
    const int k8 = cc * 2 + half;
    const bf16x8 ah = *reinterpret_cast<const bf16x8*>(sAh + (k8 * 64 + rt + l31) * 8);
    const bf16x8 al = *reinterpret_cast<const bf16x8*>(sAl + (k8 * 64 + rt + l31) * 8);
    const bf16x8 bh = *reinterpret_cast<const bf16x8*>(sBh + (k8 * 64 + tc + l31) * 8);
    const bf16x8 bl = *reinterpret_cast<const bf16x8*>(sBl + (k8 * 64 + tc + l31) * 8);
    acc = MF(ah, bh, acc); acc = MF(ah, bl, acc); acc = MF(al, bh, acc);
  }
  float T[16];
  {
    const float bv = bias[o0 + tc + l31];
#pragma unroll
    for (int i = 0; i < 16; ++i) T[i] = acc[i] + bv;
  }

  // restage B with W1
  __syncthreads();
  {
    const size_t gw = (size_t)(o0 + r) * C;
#pragma unroll
    for (int i = 0; i < K8 / 4; ++i) {
      const int k8 = k80 + 4 * i;
      stage16(sBh + (k8 * 64 + r) * 8, w1h + gw + k8 * 8);
      stage16(sBl + (k8 * 64 + r) * 8, w1l + gw + k8 * 8);
    }
  }
  __syncthreads();

  bf16x8 BH[HOIST ? K8 / 2 : 1], BL[HOIST ? K8 / 2 : 1];
  if constexpr (HOIST) {
#pragma unroll
    for (int cc = 0; cc < K8 / 2; ++cc) {
      const int k8 = cc * 2 + half;
      BH[cc] = *reinterpret_cast<const bf16x8*>(sBh + (k8 * 64 + tc + l31) * 8);
      BL[cc] = *reinterpret_cast<const bf16x8*>(sBl + (k8 * 64 + tc + l31) * 8);
    }
  }

  float mx[16], sm[16], s2[16];
#pragma unroll
  for (int i = 0; i < 16; ++i) { mx[i] = -__builtin_inff(); sm[i] = 0.f; s2[i] = 0.f; }

  const int* nrow = nbr + ((size_t)(b * NP + n0 + r)) * KK;

  for (int k = ks * KLEN; k < ks * KLEN + KLEN; ++k) {
    __syncthreads();
    {
      const int jr = nrow[k];
      const size_t gg = ((size_t)(b * NP + jr)) * 512 + colbase;
#pragma unroll
      for (int i = 0; i < K8 / 4; ++i) {
        const int k8 = k80 + 4 * i;
        stage16(sAh + (k8 * 64 + r) * 8, xh + gg + k8 * 8);
        stage16(sAl + (k8 * 64 + r) * 8, xl + gg + k8 * 8);
      }
    }
    __syncthreads();
#pragma unroll
    for (int i = 0; i < 16; ++i) acc[i] = 0.f;
#pragma unroll
    for (int cc = 0; cc < K8 / 2; ++cc) {
      const int k8 = cc * 2 + half;
      const bf16x8 ah = *reinterpret_cast<const bf16x8*>(sAh + (k8 * 64 + rt + l31) * 8);
      const bf16x8 al = *reinterpret_cast<const bf16x8*>(sAl + (k8 * 64 + rt + l31) * 8);
      bf16x8 bh, bl;
      if constexpr (HOIST) {
        bh = BH[cc]; bl = BL[cc];
      } else {
        bh = *reinterpret_cast<const bf16x8*>(sBh + (k8 * 64 + tc + l31) * 8);
        bl = *reinterpret_cast<const bf16x8*>(sBl + (k8 * 64 + tc + l31) * 8);
      }
      acc = MF(ah, bh, acc); acc = MF(ah, bl, acc); acc = MF(al, bh, acc);
    }
#pragma unroll
    for (int i = 0; i < 16; ++i) {
      const float h = acc[i] + T[i];
      mx[i] = fmaxf(mx[i], h);
      sm[i] += h;
      s2[i] = fmaf(h, h, s2[i]);
    }
  }

  {
    float* dst = (ks == 0) ? fA : ((ks == 1) ? fB : ((ks == 2) ? fC : fD));
    const int col = o0 + tc + l31;
#pragma unroll
    for (int i = 0; i < 16; ++i) {
      const int row = n0 + rt + (i & 3) + 8 * (i >> 2) + 4 * half;
      dst[((size_t)(b * NP + row)) * O + col] = mx[i];
    }
  }

  float S = 0.f, Q = 0.f;
#pragma unroll
  for (int i = 0; i < 16; ++i) { S += sm[i]; Q += s2[i]; }
  S += __shfl_xor(S, 32);
  Q += __shfl_xor(Q, 32);
  __syncthreads();
  float* fs = reinterpret_cast<float*>(sb);
  fs[w * 32 + l31] = S;
  fs[128 + w * 32 + l31] = Q;
  __syncthreads();
  if (t < 64) {
    atomicAdd(ssum + o0 + t, fs[t] + fs[64 + t]);
    atomicAdd(ssq + o0 + t, fs[128 + t] + fs[128 + 64 + t]);
  }
}

// ---------------- bn + leaky relu -> bf16 planes ----------------
template<int O, int NS>
__global__ __launch_bounds__(256) void bnrelu_kernel(const float* __restrict__ fA,
    const float* __restrict__ fB, const float* __restrict__ fC,
    const float* __restrict__ fD,
    const float* __restrict__ ssum, const float* __restrict__ ssq,
    const float* __restrict__ g, const float* __restrict__ be,
    unsigned short* __restrict__ xh, unsigned short* __restrict__ xl, int colbase) {
  constexpr float INV = 1.0f / 327680.0f;  // B*N*K
  const int t4 = blockIdx.x * 256 + threadIdx.x;
  const int e0 = t4 * 4;
  const int r = e0 / O, c = e0 % O;
  const size_t base = (size_t)r * O + c;
  const float4 h1 = *reinterpret_cast<const float4*>(fA + base);
  const float4 h2 = *reinterpret_cast<const float4*>(fB + base);
  float hv[4] = {fmaxf(h1.x, h2.x), fmaxf(h1.y, h2.y), fmaxf(h1.z, h2.z), fmaxf(h1.w, h2.w)};
  if constexpr (NS >= 4) {
    const float4 h3 = *reinterpret_cast<const float4*>(fC + base);
    const float4 h4 = *reinterpret_cast<const float4*>(fD + base);
    hv[0] = fmaxf(fmaxf(hv[0], h3.x), h4.x);
    hv[1] = fmaxf(fmaxf(hv[1], h3.y), h4.y);
    hv[2] = fmaxf(fmaxf(hv[2], h3.z), h4.z);
    hv[3] = fmaxf(fmaxf(hv[3], h3.w), h4.w);
  }
  unsigned short hh[4], ll[4];
#pragma unroll
  for (int j = 0; j < 4; ++j) {
    const int col = c + j;
    const float m = ssum[col] * INV;
    const float v = ssq[col] * INV - m * m;
    const float sc = g[col] / sqrtf(v + 1e-5f);
    float val = (hv[j] - m) * sc + be[col];
    val = (val >= 0.f) ? val : 0.2f * val;
    split2(val, hh[j], ll[j]);
  }
  const size_t ob = (size_t)r * 512 + colbase + c;
  uint2 ph, pl;
  ph.x = (unsigned)hh[0] | ((unsigned)hh[1] << 16);
  ph.y = (unsigned)hh[2] | ((unsigned)hh[3] << 16);
  pl.x = (unsigned)ll[0] | ((unsigned)ll[1] << 16);
  pl.y = (unsigned)ll[2] | ((unsigned)ll[3] << 16);
  *reinterpret_cast<uint2*>(xh + ob) = ph;
  *reinterpret_cast<uint2*>(xl + ob) = pl;
}

// ---------------- final conv + global max pool (MFMA) ----------------
__global__ __launch_bounds__(256) void final_mfma(const unsigned short* __restrict__ xh,
    const unsigned short* __restrict__ xl, const unsigned short* __restrict__ wfh,
    const unsigned short* __restrict__ wfl, unsigned* __restrict__ outenc) {
  __shared__ __align__(16) unsigned short sb[4 * 4096];
  __shared__ float fr[128];
  unsigned short* sAh = sb;
  unsigned short* sAl = sb + 4096;
  unsigned short* sBh = sb + 8192;
  unsigned short* sBl = sb + 12288;
  const int t = threadIdx.x, lane = t & 63, w = t >> 6;
  const int half = lane >> 5, l31 = lane & 31;
  const int rt = (w >> 1) * 32, tc = (w & 1) * 32;
  const int b = blockIdx.z, n0 = blockIdx.x * 64, o0 = blockIdx.y * 64;
  const int r = t & 63, k80 = t >> 6;

  f32x16 acc;
#pragma unroll
  for (int i = 0; i < 16; ++i) acc[i] = 0.f;

  for (int cc = 0; cc < 8; ++cc) {
    __syncthreads();
    const size_t ga = ((size_t)(b * NP + n0 + r)) * 512 + cc * 64;
    const size_t gb = ((size_t)(o0 + r)) * 512 + cc * 64;
#pragma unroll
    for (int i = 0; i < 2; ++i) {
      const int k8 = k80 + 4 * i;
      stage16(sAh + (k8 * 64 + r) * 8, xh + ga + k8 * 8);
      stage16(sAl + (k8 * 64 + r) * 8, xl + ga + k8 * 8);
      stage16(sBh + (k8 * 64 + r) * 8, wfh + gb + k8 * 8);
      stage16(sBl + (k8 * 64 + r) * 8, wfl + gb + k8 * 8);
    }
    __syncthreads();
#pragma unroll
    for (int ch = 0; ch < 4; ++ch) {
      const int k8 = ch * 2 + half;
      const bf16x8 ah = *reinterpret_cast<const bf16x8*>(sAh + (k8 * 64 + rt + l31) * 8);
      const bf16x8 al = *reinterpret_cast<const bf16x8*>(sAl + (k8 * 64 + rt + l31) * 8);
      const bf16x8 bh = *reinterpret_cast<const bf16x8*>(sBh + (k8 * 64 + tc + l31) * 8);
      const bf16x8 bl = *reinterpret_cast<const bf16x8*>(sBl + (k8 * 64 + tc + l31) * 8);
      acc = MF(ah, bh, acc); acc = MF(ah, bl, acc); acc = MF(al, bh, acc);
    }
  }
  float M = acc[0];
#pragma unroll
  for (int i = 1; i < 16; ++i) M = fmaxf(M, acc[i]);
  M = fmaxf(M, __shfl_xor(M, 32));
  fr[w * 32 + l31] = M;
  __syncthreads();
  if (t < 64) {
    const float Mc = fmaxf(fr[t], fr[64 + t]);
    const unsigned ub = __float_as_uint(Mc);
    const unsigned key = (ub & 0x80000000u) ? ~ub : (ub | 0x80000000u);
    atomicMax(outenc + b * 1024 + o0 + t, key);
  }
}

__global__ __launch_bounds__(256) void decode_kernel(const unsigned int* __restrict__ enc,
    const float* __restrict__ bf, float* __restrict__ out) {
  const int gid = blockIdx.x * 256 + threadIdx.x;  // 8192
  const unsigned key = enc[gid];
  const unsigned ubits = (key & 0x80000000u) ? (key & 0x7fffffffu) : ~key;
  out[gid] = __uint_as_float(ubits) + bf[gid & 1023];
}

// ---------------- launch ----------------
extern "C" void kernel_launch(void* const* d_in, const int* in_sizes, int n_in,
                              void* d_out, int out_size, void* d_ws, size_t ws_size,
                              hipStream_t stream) {
  (void)in_sizes; (void)n_in; (void)out_size; (void)ws_size;
  const float* x   = (const float*)d_in[0];
  const float* W0  = (const float*)d_in[1];
  const float* b0  = (const float*)d_in[2];
  const float* g0  = (const float*)d_in[3];
  const float* be0 = (const float*)d_in[4];
  const float* W1  = (const float*)d_in[5];
  const float* b1  = (const float*)d_in[6];
  const float* g1  = (const float*)d_in[7];
  const float* be1 = (const float*)d_in[8];
  const float* W2  = (const float*)d_in[9];
  const float* b2  = (const float*)d_in[10];
  const float* g2  = (const float*)d_in[11];
  const float* be2 = (const float*)d_in[12];
  const float* W3  = (const float*)d_in[13];
  const float* b3  = (const float*)d_in[14];
  const float* g3  = (const float*)d_in[15];
  const float* be3 = (const float*)d_in[16];
  const float* Wf  = (const float*)d_in[17];
  const float* bf  = (const float*)d_in[18];

  float* wsf = (float*)d_ws;
  int* idxb = (int*)d_ws;                               // 327,680 ints
  float* norms = wsf + 327680;                          // 16384
  float* stats = norms + 16384;                         // 2048
  unsigned* outenc = (unsigned*)(stats + 2048);         // 8192
  float* x4 = (float*)(outenc + 8192);                  // 65536
  float* featA = x4 + 65536;                            // 16384*256
  float* negd = featA + (size_t)4194304;                // 2*2048*2048 (33.5 MB)
  float* featB = negd;                                  // aliases negd
  float* featC = negd + 4194304;
  float* featD = featC + 1048576;
  unsigned short* xh = (unsigned short*)(negd + 8388608);  // [16384][512]
  unsigned short* xl = xh + 8388608;
  unsigned short* wb1 = xl + 8388608;                   // L1: 4 * 64*64
  unsigned short* wb2 = wb1 + 16384;                    // L2: 4 * 128*64
  unsigned short* wb3 = wb2 + 32768;                    // L3: 4 * 256*128
  unsigned short* wfh = wb3 + 131072;                   // 1024*512
  unsigned short* wfl = wfh + 524288;

  hipMemsetAsync(stats, 0, 2048 * sizeof(float), stream);
  hipMemsetAsync(outenc, 0, 8192 * sizeof(unsigned), stream);

  const dim3 blk(256, 1, 1);
  const dim3 ggrid(32, 32, 2);
  const dim3 sgrid(1024, 1, 1);

  pad_kernel<<<dim3(64), blk, 0, stream>>>(x, x4);
  wsplit_conv<64, 64><<<dim3(16), blk, 0, stream>>>(W1, wb1, wb1 + 4096, wb1 + 8192, wb1 + 12288);
  wsplit_conv<128, 64><<<dim3(32), blk, 0, stream>>>(W2, wb2, wb2 + 8192, wb2 + 16384, wb2 + 24576);
  wsplit_conv<256, 128><<<dim3(128), blk, 0, stream>>>(W3, wb3, wb3 + 32768, wb3 + 65536, wb3 + 98304);
  wsplit_final<<<dim3(2048), blk, 0, stream>>>(Wf, wfh, wfl);

  // Layer 0 (C=3 -> 64, out cols [0,64))
  norms4_kernel<<<dim3(64), blk, 0, stream>>>(x4, norms);
  for (int cb = 0; cb < 4; ++cb) {
    dist0_kernel<<<ggrid, blk, 0, stream>>>(x4, norms, negd, 2 * cb);
    knn_select_kernel<<<sgrid, blk, 0, stream>>>(negd, idxb, 2 * cb);
  }
  conv0_kernel<<<dim3(32, 4, 8), blk, 0, stream>>>(x, idxb, W0, b0, featA, featB, featC, featD,
                                                   stats, stats + 256);
  bnrelu_kernel<64, 4><<<dim3(1024), blk, 0, stream>>>(featA, featB, featC, featD,
      stats, stats + 256, g0, be0, xh, xl, 0);

  // Layer 1 (64 -> 64, in cols [0,64), out [64,128))
  norms_planes<64><<<dim3(64), blk, 0, stream>>>(xh, xl, 0, norms);
  for (int cb = 0; cb < 4; ++cb) {
    dist_mfma<64><<<ggrid, blk, 0, stream>>>(xh, xl, 0, norms, negd, 2 * cb);
    knn_select_kernel<<<sgrid, blk, 0, stream>>>(negd, idxb, 2 * cb);
  }
  conv_mfma<64, 64, 4, false><<<dim3(32, 4, 8), blk, 0, stream>>>(xh, xl, 0, idxb,
      wb1, wb1 + 4096, wb1 + 8192, wb1 + 12288, b1, featA, featB, featC, featD,
      stats + 512, stats + 768);
  bnrelu_kernel<64, 4><<<dim3(1024), blk, 0, stream>>>(featA, featB, featC, featD,
      stats + 512, stats + 768, g1, be1, xh, xl, 64);

  // Layer 2 (64 -> 128, in cols [64,128), out [128,256))
  norms_planes<64><<<dim3(64), blk, 0, stream>>>(xh, xl, 64, norms);
  for (int cb = 0; cb < 4; ++cb) {
    dist_mfma<64><<<ggrid, blk, 0, stream>>>(xh, xl, 64, norms, negd, 2 * cb);
    knn_select_kernel<<<sgrid, blk, 0, stream>>>(negd, idxb, 2 * cb);
  }
  conv_mfma<64, 128, 2, false><<<dim3(32, 4, 8), blk, 0, stream>>>(xh, xl, 64, idxb,
      wb2, wb2 + 8192, wb2 + 16384, wb2 + 24576, b2, featA, featB, featC, featD,
      stats + 1024, stats + 1280);
  bnrelu_kernel<128, 2><<<dim3(2048), blk, 0, stream>>>(featA, featB, featC, featD,
      stats + 1024, stats + 1280, g2, be2, xh, xl, 128);

  // Layer 3 (128 -> 256, in cols [128,256), out [256,512))
  norms_planes<128><<<dim3(64), blk, 0, stream>>>(xh, xl, 128, norms);
  for (int cb = 0; cb < 4; ++cb) {
    dist_mfma<128><<<ggrid, blk, 0, stream>>>(xh, xl, 128, norms, negd, 2 * cb);
    knn_select_kernel<<<sgrid, blk, 0, stream>>>(negd, idxb, 2 * cb);
  }
  conv_mfma<128, 256, 2, true><<<dim3(32, 8, 8), blk, 0, stream>>>(xh, xl, 128, idxb,
      wb3, wb3 + 32768, wb3 + 65536, wb3 + 98304, b3, featA, featB, featC, featD,
      stats + 1536, stats + 1792);
  bnrelu_kernel<256, 2><<<dim3(4096), blk, 0, stream>>>(featA, featB, featC, featD,
      stats + 1536, stats + 1792, g3, be3, xh, xl, 256);

  // Final 1x1 conv + global max pool
  final_mfma<<<dim3(32, 16, 8), blk, 0, stream>>>(xh, xl, wfh, wfl, outenc);
  decode_kernel<<<dim3(32), blk, 0, stream>>>(outenc, bf, (float*)d_out);
}